// Round 13
// baseline (277.187 us; speedup 1.0000x reference)
//
#include <hip/hip_runtime.h>
#include <math.h>

#define NNODES 100000
#define NEDGES 3200000
#define ETOT   (NEDGES + NNODES)
#define IN_DIM 128
#define NH1    8
#define NC1    8
#define HC     64
#define OUTC   2
#define NEGSL  0.2f
#define L2E    1.44269504f

// counting-sort CSR build parameters
#define NBUCK 391                 // ceil(NNODES/256) coarse buckets (dst>>8)
#define EPB   4096                // edges per block in hist/scatter
#define NBLK  782                 // ceil(NEDGES/EPB)
#define TOTC  (NBUCK * NBLK)      // 305762 (bucket-major counts array)

// ---------------- CSR build (two-level LDS counting sort) ----------------

// per-block LDS histogram over coarse buckets -> counts[bucket][block]
__global__ __launch_bounds__(512) void histA(const int* __restrict__ ei,
                                             int* __restrict__ carr) {
    __shared__ int lh[NBUCK];
    int tid = threadIdx.x;
    for (int i = tid; i < NBUCK; i += 512) lh[i] = 0;
    __syncthreads();
    const int* dptr = ei + NEDGES;
    int base = blockIdx.x * EPB;
#pragma unroll
    for (int i = 0; i < EPB / 2048; i++) {
        int idx = base + i * 2048 + tid * 4;
        if (idx < NEDGES) {
            int4 d4 = *(const int4*)&dptr[idx];
            atomicAdd(&lh[d4.x >> 8], 1);
            atomicAdd(&lh[d4.y >> 8], 1);
            atomicAdd(&lh[d4.z >> 8], 1);
            atomicAdd(&lh[d4.w >> 8], 1);
        }
    }
    __syncthreads();
    for (int i = tid; i < NBUCK; i += 512)
        carr[i * NBLK + blockIdx.x] = lh[i];
}

// exclusive scan over TOTC counts (block-local) + block sums
__global__ __launch_bounds__(256) void scanA(int* __restrict__ carr,
                                             int* __restrict__ bsums) {
    int gid = blockIdx.x * 256 + threadIdx.x;
    int v = (gid < TOTC) ? carr[gid] : 0;
    int lane = threadIdx.x & 63, w = threadIdx.x >> 6;
    int x = v;
    for (int off = 1; off < 64; off <<= 1) {
        int y = __shfl_up(x, off, 64);
        if (lane >= off) x += y;
    }
    __shared__ int wt[4];
    if (lane == 63) wt[w] = x;
    __syncthreads();
    int add = 0;
    for (int i = 0; i < w; i++) add += wt[i];
    int incl = x + add;
    if (gid < TOTC) carr[gid] = incl - v;
    if (threadIdx.x == 255) bsums[blockIdx.x] = incl;
}

// scan of block sums; 4 elements per thread (supports nb <= 4096)
__global__ __launch_bounds__(1024) void scanB(int* __restrict__ bsums, int nb) {
    int tid = threadIdx.x;
    int base = tid * 4;
    int v[4]; int tot = 0;
#pragma unroll
    for (int j = 0; j < 4; j++) {
        v[j] = (base + j < nb) ? bsums[base + j] : 0;
        tot += v[j];
    }
    int lane = tid & 63, w = tid >> 6;
    int x = tot;
    for (int off = 1; off < 64; off <<= 1) {
        int y = __shfl_up(x, off, 64);
        if (lane >= off) x += y;
    }
    __shared__ int wt[16];
    if (lane == 63) wt[w] = x;
    __syncthreads();
    int add = 0;
    for (int i = 0; i < w; i++) add += wt[i];
    int pre = x + add - tot;
#pragma unroll
    for (int j = 0; j < 4; j++) {
        if (base + j < nb) bsums[base + j] = pre;
        pre += v[j];
    }
}

// scatter edges into bucket-contiguous regions (global offset = carr + bsums,
// fused — no scanC pass); rank via LDS atomic. Pack src | dst_low8 << 17.
__global__ __launch_bounds__(512) void scatC(const int* __restrict__ ei,
                                             const int* __restrict__ carr,
                                             const int* __restrict__ bsums,
                                             int* __restrict__ ebuf) {
    __shared__ int soffL[NBUCK];
    __shared__ int lh[NBUCK];
    int tid = threadIdx.x;
    for (int i = tid; i < NBUCK; i += 512) {
        int g = i * NBLK + blockIdx.x;
        soffL[i] = carr[g] + bsums[g >> 8];
        lh[i] = 0;
    }
    __syncthreads();
    int base = blockIdx.x * EPB;
#pragma unroll
    for (int i = 0; i < EPB / 2048; i++) {
        int idx = base + i * 2048 + tid * 4;
        if (idx < NEDGES) {
            int4 s4 = *(const int4*)&ei[idx];
            int4 d4 = *(const int4*)&ei[NEDGES + idx];
            int b0 = d4.x >> 8, b1 = d4.y >> 8, b2 = d4.z >> 8, b3 = d4.w >> 8;
            int r0 = atomicAdd(&lh[b0], 1);
            int r1 = atomicAdd(&lh[b1], 1);
            int r2 = atomicAdd(&lh[b2], 1);
            int r3 = atomicAdd(&lh[b3], 1);
            ebuf[soffL[b0] + r0] = s4.x | ((d4.x & 255) << 17);
            ebuf[soffL[b1] + r1] = s4.y | ((d4.y & 255) << 17);
            ebuf[soffL[b2] + r2] = s4.z | ((d4.z & 255) << 17);
            ebuf[soffL[b3] + r3] = s4.w | ((d4.w & 255) << 17);
        }
    }
}

// one block per bucket (512 threads): fine count (256 nodes), LDS scan
// (+1 self-loop per node), emit rowoff + self-loops + final srcs.
__global__ __launch_bounds__(512) void buildD(const int* __restrict__ carr,
                                              const int* __restrict__ bsums,
                                              const int* __restrict__ ebuf,
                                              int* __restrict__ rowoff,
                                              int* __restrict__ srcs) {
    int b = blockIdx.x, tid = threadIdx.x;
    int nb = min(256, NNODES - b * 256);
    int g0 = b * NBLK;
    int ebeg = carr[g0] + bsums[g0 >> 8];
    int eend = (b == NBUCK - 1) ? NEDGES
                                : (carr[g0 + NBLK] + bsums[(g0 + NBLK) >> 8]);
    __shared__ int cnt2[256];
    __shared__ int rowL[256];
    __shared__ int wsum[4];
    if (tid < 256) cnt2[tid] = 0;
    __syncthreads();
    for (int e = ebeg + tid; e < eend; e += 512)
        atomicAdd(&cnt2[(ebuf[e] >> 17) & 255], 1);
    __syncthreads();
    // exclusive scan of (cnt2 + 1) on waves 0-3
    int lane = tid & 63, w4 = tid >> 6;
    int v = 0, x = 0;
    if (tid < 256) {
        v = (tid < nb) ? cnt2[tid] + 1 : 0;
        x = v;
        for (int off = 1; off < 64; off <<= 1) {
            int y = __shfl_up(x, off, 64);
            if (lane >= off) x += y;
        }
        if (lane == 63) wsum[w4] = x;
    }
    __syncthreads();
    if (tid < 256) {
        int add = 0;
        for (int i = 0; i < w4; i++) add += wsum[i];
        int row = ebeg + b * 256 + x + add - v;  // + earlier buckets' self-loops
        if (tid < nb) {
            rowL[tid] = row;
            int gnode = b * 256 + tid;
            rowoff[gnode] = row;
            srcs[row + cnt2[tid]] = gnode;       // self-loop in last slot
            if (gnode == NNODES - 1) rowoff[NNODES] = ETOT;
        }
    }
    __syncthreads();
    if (tid < 256) cnt2[tid] = 0;                // reuse as rank counters
    __syncthreads();
    for (int e = ebeg + tid; e < eend; e += 512) {
        int wv = ebuf[e];
        int dl = (wv >> 17) & 255;
        int r = atomicAdd(&cnt2[dl], 1);
        srcs[rowL[dl] + r] = wv & 0x1FFFF;
    }
}

// ---------------- layer 1 linear + attention logit exponentials ----------------
// 32 nodes per block (8 per wave) — halves W1-staging cost per node.
// h1 stored as bf16 (RNE). alE[node*8+h] = (exp(al_src), exp(0.2*al_src)).

__global__ __launch_bounds__(256) void gemm1(const float* __restrict__ x,
                                             const float* __restrict__ W1,
                                             const float* __restrict__ a1s,
                                             const float* __restrict__ a1d,
                                             unsigned short* __restrict__ h1b,
                                             float2* __restrict__ alE,
                                             float* __restrict__ al1d) {
    __shared__ float sW[IN_DIM * HC];   // 32 KB
    int tid = threadIdx.x;
    const float4* W4 = (const float4*)W1;
    float4* sW4 = (float4*)sW;
#pragma unroll
    for (int i = 0; i < 8; i++)
        sW4[tid + i * 256] = W4[tid + i * 256];
    __syncthreads();

    int w = __builtin_amdgcn_readfirstlane(tid >> 6);
    int lane = tid & 63;
    int node0 = blockIdx.x * 32 + w * 8;       // 3125 blocks * 32 = 100000 exact
    const float* xr = x + (size_t)node0 * IN_DIM;

    float acc[8] = {0.f, 0.f, 0.f, 0.f, 0.f, 0.f, 0.f, 0.f};
#pragma unroll 4
    for (int k = 0; k < IN_DIM; k++) {
        float wv = sW[k * HC + lane];
#pragma unroll
        for (int j = 0; j < 8; j++)
            acc[j] = fmaf(xr[j * IN_DIM + k], wv, acc[j]);
    }

    int head = lane >> 3, c = lane & 7;
    float as = a1s[head * NC1 + c], adv = a1d[head * NC1 + c];
#pragma unroll
    for (int n = 0; n < 8; n++) {
        int node = node0 + n;
        unsigned int u = __float_as_uint(acc[n]);
        h1b[node * HC + lane] =
            (unsigned short)((u + 0x7FFF + ((u >> 16) & 1)) >> 16);  // RNE bf16
        float ps = acc[n] * as;
        float pd = acc[n] * adv;
        for (int off = 1; off < 8; off <<= 1) {
            ps += __shfl_xor(ps, off, 64);
            pd += __shfl_xor(pd, off, 64);
        }
        if (c == 0) {
            alE[node * NH1 + head] = make_float2(exp2f(ps * L2E),
                                                 exp2f(ps * (NEGSL * L2E)));
            al1d[node * NH1 + head] = pd;
        }
    }
}

// ---------------- layer 1 aggregation (R11 structure — best measured) ----------------
// wave per node; TWO edges per wave-instruction: lane = ep*32 + c where
// ep = edge parity, c = channel pair (channels 2c,2c+1; head = c>>2).
// exp(LeakyReLU(als+ald)) == max(E1s*E1d, E2s*E2d); shift cancels in acc/den.

__global__ __launch_bounds__(256) void agg1(const unsigned short* __restrict__ h1b,
                                            const float2* __restrict__ alE,
                                            const float* __restrict__ al1d,
                                            const float* __restrict__ b1,
                                            const float* __restrict__ W2,
                                            const float* __restrict__ a2s,
                                            const float* __restrict__ a2d,
                                            const int* __restrict__ rowoff,
                                            const int* __restrict__ srcs,
                                            float4* __restrict__ nd2,
                                            float* __restrict__ al2d) {
    int w = threadIdx.x >> 6, lane = threadIdx.x & 63;
    int node = blockIdx.x * 4 + w;
    if (node >= NNODES) return;
    int ep = lane >> 5;          // which edge of the pair
    int c  = lane & 31;          // channel pair id: channels 2c, 2c+1
    int hh = c >> 2;             // head of both channels
    float ald = al1d[node * NH1 + hh];
    float E1d = exp2f(ald * L2E);
    float E2d = exp2f(ald * (NEGSL * L2E));
    int beg = __builtin_amdgcn_readfirstlane(rowoff[node]);
    int end = __builtin_amdgcn_readfirstlane(rowoff[node + 1]);

    float den = 0.f, acc0 = 0.f, acc1 = 0.f;
    float denB = 0.f, acc0B = 0.f, acc1B = 0.f;
    int i = beg;
    for (; i + 4 <= end; i += 4) {
        int sa = srcs[i + ep];
        int sb = srcs[i + 2 + ep];
        float2 ea = alE[sa * NH1 + hh];
        float2 eb = alE[sb * NH1 + hh];
        unsigned int ha = *(const unsigned int*)&h1b[sa * HC + 2 * c];
        unsigned int hb = *(const unsigned int*)&h1b[sb * HC + 2 * c];
        float pa = fmaxf(ea.x * E1d, ea.y * E2d);
        float pb = fmaxf(eb.x * E1d, eb.y * E2d);
        float va0 = __uint_as_float(ha << 16);
        float va1 = __uint_as_float(ha & 0xFFFF0000u);
        float vb0 = __uint_as_float(hb << 16);
        float vb1 = __uint_as_float(hb & 0xFFFF0000u);
        den  += pa;  acc0  = fmaf(pa, va0, acc0);  acc1  = fmaf(pa, va1, acc1);
        denB += pb;  acc0B = fmaf(pb, vb0, acc0B); acc1B = fmaf(pb, vb1, acc1B);
    }
    for (; i < end; i += 2) {
        int ia = i + ep;
        bool valid = ia < end;
        int sa = srcs[valid ? ia : end - 1];
        float2 ea = alE[sa * NH1 + hh];
        unsigned int ha = *(const unsigned int*)&h1b[sa * HC + 2 * c];
        float pa = fmaxf(ea.x * E1d, ea.y * E2d);
        pa = valid ? pa : 0.f;
        float va0 = __uint_as_float(ha << 16);
        float va1 = __uint_as_float(ha & 0xFFFF0000u);
        den += pa; acc0 = fmaf(pa, va0, acc0); acc1 = fmaf(pa, va1, acc1);
    }
    den += denB; acc0 += acc0B; acc1 += acc1B;
    den  += __shfl_xor(den, 32, 64);
    acc0 += __shfl_xor(acc0, 32, 64);
    acc1 += __shfl_xor(acc1, 32, 64);

    float2 b1v = *(const float2*)&b1[2 * c];
    float o0 = acc0 / den + b1v.x;
    float o1 = acc1 / den + b1v.y;
    o0 = (o0 > 0.f) ? o0 : expm1f(o0);       // ELU
    o1 = (o1 > 0.f) ? o1 : expm1f(o1);
    float4 w2v = *(const float4*)&W2[4 * c];
    float p0 = o0 * w2v.x + o1 * w2v.z;
    float p1 = o0 * w2v.y + o1 * w2v.w;
    for (int off = 1; off < 32; off <<= 1) {
        p0 += __shfl_xor(p0, off, 64);
        p1 += __shfl_xor(p1, off, 64);
    }
    if (lane == 0) {
        float l2s = p0 * a2s[0] + p1 * a2s[1];
        float l2d = p0 * a2d[0] + p1 * a2d[1];
        nd2[node] = make_float4(exp2f(l2s * L2E), exp2f(l2s * (NEGSL * L2E)),
                                p0, p1);
        al2d[node] = l2d;
    }
}

// ---------------- layer 2 aggregation (wave per node, lane per edge) ----------------

__global__ __launch_bounds__(256) void agg2(const float4* __restrict__ nd2,
                                            const float* __restrict__ al2d,
                                            const float* __restrict__ b2,
                                            const int* __restrict__ rowoff,
                                            const int* __restrict__ srcs,
                                            float* __restrict__ out) {
    int w = threadIdx.x >> 6, lane = threadIdx.x & 63;
    int n = blockIdx.x * 4 + w;
    if (n >= NNODES) return;
    float ald = al2d[n];
    float E1d = exp2f(ald * L2E);
    float E2d = exp2f(ald * (NEGSL * L2E));
    int beg = rowoff[n], end = rowoff[n + 1];
    float den = 0.f, a0 = 0.f, a1 = 0.f;
    for (int idx = beg + lane; idx < end; idx += 64) {
        int s = srcs[idx];
        float4 nd = nd2[s];
        float p = fmaxf(nd.x * E1d, nd.y * E2d);
        den += p;
        a0 = fmaf(p, nd.z, a0);
        a1 = fmaf(p, nd.w, a1);
    }
    for (int off = 1; off < 64; off <<= 1) {
        den += __shfl_xor(den, off, 64);
        a0  += __shfl_xor(a0, off, 64);
        a1  += __shfl_xor(a1, off, 64);
    }
    if (lane == 0) {
        out[n * 2 + 0] = a0 / den + b2[0];
        out[n * 2 + 1] = a1 / den + b2[1];
    }
}

// ---------------- launch ----------------

extern "C" void kernel_launch(void* const* d_in, const int* in_sizes, int n_in,
                              void* d_out, int out_size, void* d_ws, size_t ws_size,
                              hipStream_t stream) {
    const float* x   = (const float*)d_in[0];
    const int*   ei  = (const int*)  d_in[1];
    // d_in[2] = edge_attr (unused by reference)
    const float* W1  = (const float*)d_in[3];
    const float* a1s = (const float*)d_in[4];
    const float* a1d = (const float*)d_in[5];
    const float* b1  = (const float*)d_in[6];
    const float* W2  = (const float*)d_in[7];
    const float* a2s = (const float*)d_in[8];
    const float* a2d = (const float*)d_in[9];
    const float* b2  = (const float*)d_in[10];
    float* out = (float*)d_out;

    // workspace layout. CSR scratch (ebuf/carr/bsums) aliases the h1b+alE
    // region — both are dead until gemm1, which runs after buildD.
    char* ws = (char*)d_ws;
    unsigned short* h1b = (unsigned short*)ws;               // N*64 bf16 (12.8MB)
    float2* alE   = (float2*)(ws + (size_t)NNODES * HC * 2); // N*8 float2 (6.4MB)
    float* al1d_  = (float*)(alE + (size_t)NNODES * NH1);    // N*8 (3.2MB)
    float4* nd2   = (float4*)(al1d_ + (size_t)NNODES * NH1); // N float4 (1.6MB)
    float* al2d_  = (float*)(nd2 + NNODES);                  // N
    int* rowoff   = (int*)(al2d_ + NNODES);                  // N+1
    int* srcs     = rowoff + NNODES + 1;                     // E+N (13.2MB)
    // CSR scratch aliases h1b..alE (19.2MB >= 14.1MB needed)
    int* ebuf     = (int*)ws;                                // NEDGES (12.8MB)
    int* carr     = ebuf + NEDGES;                           // TOTC (1.22MB)
    int* bsums    = carr + TOTC;                             // ~1195 ints

    const int NB_SC  = (TOTC + 255) / 256;            // 1195
    const int NB_N4  = (NNODES + 3) / 4;              // 25000
    const int NB_G   = NNODES / 32;                   // 3125 (exact)

    // CSR build (LDS counting sort; no global atomics; scanC fused)
    histA<<<NBLK, 512, 0, stream>>>(ei, carr);
    scanA<<<NB_SC, 256, 0, stream>>>(carr, bsums);
    scanB<<<1, 1024, 0, stream>>>(bsums, NB_SC);
    scatC<<<NBLK, 512, 0, stream>>>(ei, carr, bsums, ebuf);
    buildD<<<NBUCK, 512, 0, stream>>>(carr, bsums, ebuf, rowoff, srcs);

    // layer 1 linear + logit exponentials
    gemm1<<<NB_G, 256, 0, stream>>>(x, W1, a1s, a1d, h1b, alE, al1d_);

    // layer 1 aggregation + finalize + layer-2 linear/logits
    agg1<<<NB_N4, 256, 0, stream>>>(h1b, alE, al1d_, b1, W2, a2s, a2d,
                                    rowoff, srcs, nd2, al2d_);

    // layer 2 aggregation -> output
    agg2<<<NB_N4, 256, 0, stream>>>(nd2, al2d_, b2, rowoff, srcs, out);
}

// Round 14
// 269.794 us; speedup vs baseline: 1.0274x; 1.0274x over previous
//
#include <hip/hip_runtime.h>
#include <math.h>

#define NNODES 100000
#define NEDGES 3200000
#define ETOT   (NEDGES + NNODES)
#define IN_DIM 128
#define NH1    8
#define NC1    8
#define HC     64
#define OUTC   2
#define NEGSL  0.2f
#define L2E    1.44269504f

// counting-sort CSR build parameters
#define NBUCK 391                 // ceil(NNODES/256) coarse buckets (dst>>8)
#define EPB   4096                // edges per block in hist/scatter
#define NBLK  782                 // ceil(NEDGES/EPB)
#define TOTC  (NBUCK * NBLK)      // 305762 (bucket-major counts array)

// ---------------- CSR build (two-level LDS counting sort) ----------------

__global__ __launch_bounds__(256) void histA(const int* __restrict__ ei,
                                             int* __restrict__ carr) {
    __shared__ int lh[NBUCK];
    int tid = threadIdx.x;
    for (int i = tid; i < NBUCK; i += 256) lh[i] = 0;
    __syncthreads();
    const int* dptr = ei + NEDGES;
    int base = blockIdx.x * EPB;
#pragma unroll
    for (int i = 0; i < EPB / 1024; i++) {
        int idx = base + i * 1024 + tid * 4;
        if (idx < NEDGES) {
            int4 d4 = *(const int4*)&dptr[idx];
            atomicAdd(&lh[d4.x >> 8], 1);
            atomicAdd(&lh[d4.y >> 8], 1);
            atomicAdd(&lh[d4.z >> 8], 1);
            atomicAdd(&lh[d4.w >> 8], 1);
        }
    }
    __syncthreads();
    for (int i = tid; i < NBUCK; i += 256)
        carr[i * NBLK + blockIdx.x] = lh[i];
}

__global__ __launch_bounds__(256) void scanA(int* __restrict__ carr,
                                             int* __restrict__ bsums) {
    int gid = blockIdx.x * 256 + threadIdx.x;
    int v = (gid < TOTC) ? carr[gid] : 0;
    int lane = threadIdx.x & 63, w = threadIdx.x >> 6;
    int x = v;
    for (int off = 1; off < 64; off <<= 1) {
        int y = __shfl_up(x, off, 64);
        if (lane >= off) x += y;
    }
    __shared__ int wt[4];
    if (lane == 63) wt[w] = x;
    __syncthreads();
    int add = 0;
    for (int i = 0; i < w; i++) add += wt[i];
    int incl = x + add;
    if (gid < TOTC) carr[gid] = incl - v;
    if (threadIdx.x == 255) bsums[blockIdx.x] = incl;
}

__global__ __launch_bounds__(1024) void scanB(int* __restrict__ bsums, int nb) {
    int tid = threadIdx.x;
    int base = tid * 4;
    int v[4]; int tot = 0;
#pragma unroll
    for (int j = 0; j < 4; j++) {
        v[j] = (base + j < nb) ? bsums[base + j] : 0;
        tot += v[j];
    }
    int lane = tid & 63, w = tid >> 6;
    int x = tot;
    for (int off = 1; off < 64; off <<= 1) {
        int y = __shfl_up(x, off, 64);
        if (lane >= off) x += y;
    }
    __shared__ int wt[16];
    if (lane == 63) wt[w] = x;
    __syncthreads();
    int add = 0;
    for (int i = 0; i < w; i++) add += wt[i];
    int pre = x + add - tot;
#pragma unroll
    for (int j = 0; j < 4; j++) {
        if (base + j < nb) bsums[base + j] = pre;
        pre += v[j];
    }
}

__global__ __launch_bounds__(256) void scanC(int* __restrict__ carr,
                                             const int* __restrict__ bsums) {
    int gid = blockIdx.x * 256 + threadIdx.x;
    if (gid < TOTC) carr[gid] += bsums[gid >> 8];
}

__global__ __launch_bounds__(256) void scatC(const int* __restrict__ ei,
                                             const int* __restrict__ soff,
                                             int* __restrict__ ebuf) {
    __shared__ int soffL[NBUCK];
    __shared__ int lh[NBUCK];
    int tid = threadIdx.x;
    for (int i = tid; i < NBUCK; i += 256) {
        soffL[i] = soff[i * NBLK + blockIdx.x];
        lh[i] = 0;
    }
    __syncthreads();
    int base = blockIdx.x * EPB;
#pragma unroll
    for (int i = 0; i < EPB / 1024; i++) {
        int idx = base + i * 1024 + tid * 4;
        if (idx < NEDGES) {
            int4 s4 = *(const int4*)&ei[idx];
            int4 d4 = *(const int4*)&ei[NEDGES + idx];
            int b0 = d4.x >> 8, b1 = d4.y >> 8, b2 = d4.z >> 8, b3 = d4.w >> 8;
            int r0 = atomicAdd(&lh[b0], 1);
            int r1 = atomicAdd(&lh[b1], 1);
            int r2 = atomicAdd(&lh[b2], 1);
            int r3 = atomicAdd(&lh[b3], 1);
            ebuf[soffL[b0] + r0] = s4.x | ((d4.x & 255) << 17);
            ebuf[soffL[b1] + r1] = s4.y | ((d4.y & 255) << 17);
            ebuf[soffL[b2] + r2] = s4.z | ((d4.z & 255) << 17);
            ebuf[soffL[b3] + r3] = s4.w | ((d4.w & 255) << 17);
        }
    }
}

__global__ __launch_bounds__(256) void buildD(const int* __restrict__ soff,
                                              const int* __restrict__ ebuf,
                                              int* __restrict__ rowoff,
                                              int* __restrict__ srcs) {
    int b = blockIdx.x, tid = threadIdx.x;
    int nb = min(256, NNODES - b * 256);
    int ebeg = soff[b * NBLK];
    int eend = (b == NBUCK - 1) ? NEDGES : soff[(b + 1) * NBLK];
    __shared__ int cnt2[256];
    __shared__ int rowL[256];
    __shared__ int wsum[4];
    cnt2[tid] = 0;
    __syncthreads();
    for (int e = ebeg + tid; e < eend; e += 256)
        atomicAdd(&cnt2[(ebuf[e] >> 17) & 255], 1);
    __syncthreads();
    int v = (tid < nb) ? cnt2[tid] + 1 : 0;
    int lane = tid & 63, w = tid >> 6;
    int x = v;
    for (int off = 1; off < 64; off <<= 1) {
        int y = __shfl_up(x, off, 64);
        if (lane >= off) x += y;
    }
    if (lane == 63) wsum[w] = x;
    __syncthreads();
    int add = 0;
    for (int i = 0; i < w; i++) add += wsum[i];
    int fbase = ebeg + b * 256;
    int row = fbase + x + add - v;
    if (tid < nb) {
        rowL[tid] = row;
        int gnode = b * 256 + tid;
        rowoff[gnode] = row;
        srcs[row + cnt2[tid]] = gnode;
        if (gnode == NNODES - 1) rowoff[NNODES] = ETOT;
    }
    __syncthreads();
    cnt2[tid] = 0;
    __syncthreads();
    for (int e = ebeg + tid; e < eend; e += 256) {
        int wv = ebuf[e];
        int dl = (wv >> 17) & 255;
        int r = atomicAdd(&cnt2[dl], 1);
        srcs[rowL[dl] + r] = wv & 0x1FFFF;
    }
}

// ---------------- layer 1 linear + attention logit exponentials ----------------

__global__ __launch_bounds__(256) void gemm1(const float* __restrict__ x,
                                             const float* __restrict__ W1,
                                             const float* __restrict__ a1s,
                                             const float* __restrict__ a1d,
                                             unsigned short* __restrict__ h1b,
                                             float2* __restrict__ alE,
                                             float* __restrict__ al1d) {
    __shared__ float sW[IN_DIM * HC];   // 32 KB
    int tid = threadIdx.x;
    const float4* W4 = (const float4*)W1;
    float4* sW4 = (float4*)sW;
#pragma unroll
    for (int i = 0; i < 8; i++)
        sW4[tid + i * 256] = W4[tid + i * 256];
    __syncthreads();

    int w = __builtin_amdgcn_readfirstlane(tid >> 6);
    int lane = tid & 63;
    int node0 = blockIdx.x * 16 + w * 4;       // 6250 blocks * 16 = 100000 exact
    const float* xr = x + (size_t)node0 * IN_DIM;

    float acc0 = 0.f, acc1 = 0.f, acc2 = 0.f, acc3 = 0.f;
#pragma unroll 8
    for (int k = 0; k < IN_DIM; k++) {
        float wv = sW[k * HC + lane];
        acc0 = fmaf(xr[k], wv, acc0);
        acc1 = fmaf(xr[IN_DIM + k], wv, acc1);
        acc2 = fmaf(xr[2 * IN_DIM + k], wv, acc2);
        acc3 = fmaf(xr[3 * IN_DIM + k], wv, acc3);
    }

    float accs[4] = {acc0, acc1, acc2, acc3};
    int head = lane >> 3, c = lane & 7;
    float as = a1s[head * NC1 + c], adv = a1d[head * NC1 + c];
#pragma unroll
    for (int n = 0; n < 4; n++) {
        int node = node0 + n;
        unsigned int u = __float_as_uint(accs[n]);
        h1b[node * HC + lane] =
            (unsigned short)((u + 0x7FFF + ((u >> 16) & 1)) >> 16);  // RNE bf16
        float ps = accs[n] * as;
        float pd = accs[n] * adv;
        for (int off = 1; off < 8; off <<= 1) {
            ps += __shfl_xor(ps, off, 64);
            pd += __shfl_xor(pd, off, 64);
        }
        if (c == 0) {
            alE[node * NH1 + head] = make_float2(exp2f(ps * L2E),
                                                 exp2f(ps * (NEGSL * L2E)));
            al1d[node * NH1 + head] = pd;
        }
    }
}

// ---------------- layer 1 aggregation (R11 structure — best measured) ----------------
// wave per node; TWO edges per wave-instruction: lane = ep*32 + c where
// ep = edge parity, c = channel pair (channels 2c,2c+1; head = c>>2).
// exp(LeakyReLU(als+ald)) == max(E1s*E1d, E2s*E2d); shift cancels in acc/den.

__global__ __launch_bounds__(256) void agg1(const unsigned short* __restrict__ h1b,
                                            const float2* __restrict__ alE,
                                            const float* __restrict__ al1d,
                                            const float* __restrict__ b1,
                                            const float* __restrict__ W2,
                                            const float* __restrict__ a2s,
                                            const float* __restrict__ a2d,
                                            const int* __restrict__ rowoff,
                                            const int* __restrict__ srcs,
                                            float4* __restrict__ nd2,
                                            float* __restrict__ al2d) {
    int w = threadIdx.x >> 6, lane = threadIdx.x & 63;
    int node = blockIdx.x * 4 + w;
    if (node >= NNODES) return;
    int ep = lane >> 5;          // which edge of the pair
    int c  = lane & 31;          // channel pair id: channels 2c, 2c+1
    int hh = c >> 2;             // head of both channels
    float ald = al1d[node * NH1 + hh];
    float E1d = exp2f(ald * L2E);
    float E2d = exp2f(ald * (NEGSL * L2E));
    int beg = __builtin_amdgcn_readfirstlane(rowoff[node]);
    int end = __builtin_amdgcn_readfirstlane(rowoff[node + 1]);

    float den = 0.f, acc0 = 0.f, acc1 = 0.f;
    float denB = 0.f, acc0B = 0.f, acc1B = 0.f;
    int i = beg;
    for (; i + 4 <= end; i += 4) {
        int sa = srcs[i + ep];
        int sb = srcs[i + 2 + ep];
        float2 ea = alE[sa * NH1 + hh];
        float2 eb = alE[sb * NH1 + hh];
        unsigned int ha = *(const unsigned int*)&h1b[sa * HC + 2 * c];
        unsigned int hb = *(const unsigned int*)&h1b[sb * HC + 2 * c];
        float pa = fmaxf(ea.x * E1d, ea.y * E2d);
        float pb = fmaxf(eb.x * E1d, eb.y * E2d);
        float va0 = __uint_as_float(ha << 16);
        float va1 = __uint_as_float(ha & 0xFFFF0000u);
        float vb0 = __uint_as_float(hb << 16);
        float vb1 = __uint_as_float(hb & 0xFFFF0000u);
        den  += pa;  acc0  = fmaf(pa, va0, acc0);  acc1  = fmaf(pa, va1, acc1);
        denB += pb;  acc0B = fmaf(pb, vb0, acc0B); acc1B = fmaf(pb, vb1, acc1B);
    }
    for (; i < end; i += 2) {
        int ia = i + ep;
        bool valid = ia < end;
        int sa = srcs[valid ? ia : end - 1];
        float2 ea = alE[sa * NH1 + hh];
        unsigned int ha = *(const unsigned int*)&h1b[sa * HC + 2 * c];
        float pa = fmaxf(ea.x * E1d, ea.y * E2d);
        pa = valid ? pa : 0.f;
        float va0 = __uint_as_float(ha << 16);
        float va1 = __uint_as_float(ha & 0xFFFF0000u);
        den += pa; acc0 = fmaf(pa, va0, acc0); acc1 = fmaf(pa, va1, acc1);
    }
    den += denB; acc0 += acc0B; acc1 += acc1B;
    den  += __shfl_xor(den, 32, 64);
    acc0 += __shfl_xor(acc0, 32, 64);
    acc1 += __shfl_xor(acc1, 32, 64);

    float2 b1v = *(const float2*)&b1[2 * c];
    float o0 = acc0 / den + b1v.x;
    float o1 = acc1 / den + b1v.y;
    o0 = (o0 > 0.f) ? o0 : expm1f(o0);       // ELU
    o1 = (o1 > 0.f) ? o1 : expm1f(o1);
    float4 w2v = *(const float4*)&W2[4 * c];
    float p0 = o0 * w2v.x + o1 * w2v.z;
    float p1 = o0 * w2v.y + o1 * w2v.w;
    for (int off = 1; off < 32; off <<= 1) {
        p0 += __shfl_xor(p0, off, 64);
        p1 += __shfl_xor(p1, off, 64);
    }
    if (lane == 0) {
        float l2s = p0 * a2s[0] + p1 * a2s[1];
        float l2d = p0 * a2d[0] + p1 * a2d[1];
        nd2[node] = make_float4(exp2f(l2s * L2E), exp2f(l2s * (NEGSL * L2E)),
                                p0, p1);
        al2d[node] = l2d;
    }
}

// ---------------- layer 2 aggregation (wave per node, lane per edge) ----------------

__global__ __launch_bounds__(256) void agg2(const float4* __restrict__ nd2,
                                            const float* __restrict__ al2d,
                                            const float* __restrict__ b2,
                                            const int* __restrict__ rowoff,
                                            const int* __restrict__ srcs,
                                            float* __restrict__ out) {
    int w = threadIdx.x >> 6, lane = threadIdx.x & 63;
    int n = blockIdx.x * 4 + w;
    if (n >= NNODES) return;
    float ald = al2d[n];
    float E1d = exp2f(ald * L2E);
    float E2d = exp2f(ald * (NEGSL * L2E));
    int beg = rowoff[n], end = rowoff[n + 1];
    float den = 0.f, a0 = 0.f, a1 = 0.f;
    for (int idx = beg + lane; idx < end; idx += 64) {
        int s = srcs[idx];
        float4 nd = nd2[s];
        float p = fmaxf(nd.x * E1d, nd.y * E2d);
        den += p;
        a0 = fmaf(p, nd.z, a0);
        a1 = fmaf(p, nd.w, a1);
    }
    for (int off = 1; off < 64; off <<= 1) {
        den += __shfl_xor(den, off, 64);
        a0  += __shfl_xor(a0, off, 64);
        a1  += __shfl_xor(a1, off, 64);
    }
    if (lane == 0) {
        out[n * 2 + 0] = a0 / den + b2[0];
        out[n * 2 + 1] = a1 / den + b2[1];
    }
}

// ---------------- launch ----------------

extern "C" void kernel_launch(void* const* d_in, const int* in_sizes, int n_in,
                              void* d_out, int out_size, void* d_ws, size_t ws_size,
                              hipStream_t stream) {
    const float* x   = (const float*)d_in[0];
    const int*   ei  = (const int*)  d_in[1];
    // d_in[2] = edge_attr (unused by reference)
    const float* W1  = (const float*)d_in[3];
    const float* a1s = (const float*)d_in[4];
    const float* a1d = (const float*)d_in[5];
    const float* b1  = (const float*)d_in[6];
    const float* W2  = (const float*)d_in[7];
    const float* a2s = (const float*)d_in[8];
    const float* a2d = (const float*)d_in[9];
    const float* b2  = (const float*)d_in[10];
    float* out = (float*)d_out;

    // workspace layout. CSR scratch (ebuf/carr/bsums) aliases the h1b+alE
    // region — both are dead until gemm1, which runs after buildD.
    char* ws = (char*)d_ws;
    unsigned short* h1b = (unsigned short*)ws;               // N*64 bf16 (12.8MB)
    float2* alE   = (float2*)(ws + (size_t)NNODES * HC * 2); // N*8 float2 (6.4MB)
    float* al1d_  = (float*)(alE + (size_t)NNODES * NH1);    // N*8 (3.2MB)
    float4* nd2   = (float4*)(al1d_ + (size_t)NNODES * NH1); // N float4 (1.6MB)
    float* al2d_  = (float*)(nd2 + NNODES);                  // N
    int* rowoff   = (int*)(al2d_ + NNODES);                  // N+1
    int* srcs     = rowoff + NNODES + 1;                     // E+N (13.2MB)
    // CSR scratch aliases h1b..alE (19.2MB >= 14.1MB needed)
    int* ebuf     = (int*)ws;                                // NEDGES (12.8MB)
    int* carr     = ebuf + NEDGES;                           // TOTC (1.22MB)
    int* bsums    = carr + TOTC;                             // ~1195 ints

    const int NB_SC  = (TOTC + 255) / 256;            // 1195
    const int NB_N4  = (NNODES + 3) / 4;              // 25000
    const int NB_G   = NNODES / 16;                   // 6250 (exact)

    // CSR build (LDS counting sort; no global atomics)
    histA<<<NBLK, 256, 0, stream>>>(ei, carr);
    scanA<<<NB_SC, 256, 0, stream>>>(carr, bsums);
    scanB<<<1, 1024, 0, stream>>>(bsums, NB_SC);
    scanC<<<NB_SC, 256, 0, stream>>>(carr, bsums);
    scatC<<<NBLK, 256, 0, stream>>>(ei, carr, ebuf);
    buildD<<<NBUCK, 256, 0, stream>>>(carr, ebuf, rowoff, srcs);

    // layer 1 linear + logit exponentials
    gemm1<<<NB_G, 256, 0, stream>>>(x, W1, a1s, a1d, h1b, alE, al1d_);

    // layer 1 aggregation + finalize + layer-2 linear/logits
    agg1<<<NB_N4, 256, 0, stream>>>(h1b, alE, al1d_, b1, W2, a2s, a2d,
                                    rowoff, srcs, nd2, al2d_);

    // layer 2 aggregation -> output
    agg2<<<NB_N4, 256, 0, stream>>>(nd2, al2d_, b2, rowoff, srcs, out);
}

// Round 15
// 269.009 us; speedup vs baseline: 1.0304x; 1.0029x over previous
//
#include <hip/hip_runtime.h>
#include <math.h>

#define NNODES 100000
#define NEDGES 3200000
#define ETOT   (NEDGES + NNODES)
#define IN_DIM 128
#define NH1    8
#define NC1    8
#define HC     64
#define OUTC   2
#define NEGSL  0.2f
#define L2E    1.44269504f

// counting-sort CSR build parameters
#define NBUCK 391                 // ceil(NNODES/256) coarse buckets (dst>>8)
#define EPB   4096                // edges per block in hist/scatter
#define NBLK  782                 // ceil(NEDGES/EPB)
#define TOTC  (NBUCK * NBLK)      // 305762 (bucket-major counts array)

// ---------------- CSR build (two-level LDS counting sort) ----------------

__global__ __launch_bounds__(256) void histA(const int* __restrict__ ei,
                                             int* __restrict__ carr) {
    __shared__ int lh[NBUCK];
    int tid = threadIdx.x;
    for (int i = tid; i < NBUCK; i += 256) lh[i] = 0;
    __syncthreads();
    const int* dptr = ei + NEDGES;
    int base = blockIdx.x * EPB;
#pragma unroll
    for (int i = 0; i < EPB / 1024; i++) {
        int idx = base + i * 1024 + tid * 4;
        if (idx < NEDGES) {
            int4 d4 = *(const int4*)&dptr[idx];
            atomicAdd(&lh[d4.x >> 8], 1);
            atomicAdd(&lh[d4.y >> 8], 1);
            atomicAdd(&lh[d4.z >> 8], 1);
            atomicAdd(&lh[d4.w >> 8], 1);
        }
    }
    __syncthreads();
    for (int i = tid; i < NBUCK; i += 256)
        carr[i * NBLK + blockIdx.x] = lh[i];
}

__global__ __launch_bounds__(256) void scanA(int* __restrict__ carr,
                                             int* __restrict__ bsums) {
    int gid = blockIdx.x * 256 + threadIdx.x;
    int v = (gid < TOTC) ? carr[gid] : 0;
    int lane = threadIdx.x & 63, w = threadIdx.x >> 6;
    int x = v;
    for (int off = 1; off < 64; off <<= 1) {
        int y = __shfl_up(x, off, 64);
        if (lane >= off) x += y;
    }
    __shared__ int wt[4];
    if (lane == 63) wt[w] = x;
    __syncthreads();
    int add = 0;
    for (int i = 0; i < w; i++) add += wt[i];
    int incl = x + add;
    if (gid < TOTC) carr[gid] = incl - v;
    if (threadIdx.x == 255) bsums[blockIdx.x] = incl;
}

__global__ __launch_bounds__(1024) void scanB(int* __restrict__ bsums, int nb) {
    int tid = threadIdx.x;
    int base = tid * 4;
    int v[4]; int tot = 0;
#pragma unroll
    for (int j = 0; j < 4; j++) {
        v[j] = (base + j < nb) ? bsums[base + j] : 0;
        tot += v[j];
    }
    int lane = tid & 63, w = tid >> 6;
    int x = tot;
    for (int off = 1; off < 64; off <<= 1) {
        int y = __shfl_up(x, off, 64);
        if (lane >= off) x += y;
    }
    __shared__ int wt[16];
    if (lane == 63) wt[w] = x;
    __syncthreads();
    int add = 0;
    for (int i = 0; i < w; i++) add += wt[i];
    int pre = x + add - tot;
#pragma unroll
    for (int j = 0; j < 4; j++) {
        if (base + j < nb) bsums[base + j] = pre;
        pre += v[j];
    }
}

__global__ __launch_bounds__(256) void scanC(int* __restrict__ carr,
                                             const int* __restrict__ bsums) {
    int gid = blockIdx.x * 256 + threadIdx.x;
    if (gid < TOTC) carr[gid] += bsums[gid >> 8];
}

__global__ __launch_bounds__(256) void scatC(const int* __restrict__ ei,
                                             const int* __restrict__ soff,
                                             int* __restrict__ ebuf) {
    __shared__ int soffL[NBUCK];
    __shared__ int lh[NBUCK];
    int tid = threadIdx.x;
    for (int i = tid; i < NBUCK; i += 256) {
        soffL[i] = soff[i * NBLK + blockIdx.x];
        lh[i] = 0;
    }
    __syncthreads();
    int base = blockIdx.x * EPB;
#pragma unroll
    for (int i = 0; i < EPB / 1024; i++) {
        int idx = base + i * 1024 + tid * 4;
        if (idx < NEDGES) {
            int4 s4 = *(const int4*)&ei[idx];
            int4 d4 = *(const int4*)&ei[NEDGES + idx];
            int b0 = d4.x >> 8, b1 = d4.y >> 8, b2 = d4.z >> 8, b3 = d4.w >> 8;
            int r0 = atomicAdd(&lh[b0], 1);
            int r1 = atomicAdd(&lh[b1], 1);
            int r2 = atomicAdd(&lh[b2], 1);
            int r3 = atomicAdd(&lh[b3], 1);
            ebuf[soffL[b0] + r0] = s4.x | ((d4.x & 255) << 17);
            ebuf[soffL[b1] + r1] = s4.y | ((d4.y & 255) << 17);
            ebuf[soffL[b2] + r2] = s4.z | ((d4.z & 255) << 17);
            ebuf[soffL[b3] + r3] = s4.w | ((d4.w & 255) << 17);
        }
    }
}

__global__ __launch_bounds__(256) void buildD(const int* __restrict__ soff,
                                              const int* __restrict__ ebuf,
                                              int* __restrict__ rowoff,
                                              int* __restrict__ srcs) {
    int b = blockIdx.x, tid = threadIdx.x;
    int nb = min(256, NNODES - b * 256);
    int ebeg = soff[b * NBLK];
    int eend = (b == NBUCK - 1) ? NEDGES : soff[(b + 1) * NBLK];
    __shared__ int cnt2[256];
    __shared__ int rowL[256];
    __shared__ int wsum[4];
    cnt2[tid] = 0;
    __syncthreads();
    for (int e = ebeg + tid; e < eend; e += 256)
        atomicAdd(&cnt2[(ebuf[e] >> 17) & 255], 1);
    __syncthreads();
    int v = (tid < nb) ? cnt2[tid] + 1 : 0;
    int lane = tid & 63, w = tid >> 6;
    int x = v;
    for (int off = 1; off < 64; off <<= 1) {
        int y = __shfl_up(x, off, 64);
        if (lane >= off) x += y;
    }
    if (lane == 63) wsum[w] = x;
    __syncthreads();
    int add = 0;
    for (int i = 0; i < w; i++) add += wsum[i];
    int fbase = ebeg + b * 256;
    int row = fbase + x + add - v;
    if (tid < nb) {
        rowL[tid] = row;
        int gnode = b * 256 + tid;
        rowoff[gnode] = row;
        srcs[row + cnt2[tid]] = gnode;
        if (gnode == NNODES - 1) rowoff[NNODES] = ETOT;
    }
    __syncthreads();
    cnt2[tid] = 0;
    __syncthreads();
    for (int e = ebeg + tid; e < eend; e += 256) {
        int wv = ebuf[e];
        int dl = (wv >> 17) & 255;
        int r = atomicAdd(&cnt2[dl], 1);
        srcs[rowL[dl] + r] = wv & 0x1FFFF;
    }
}

// ---------------- layer 1 linear + attention logit exponentials ----------------

__global__ __launch_bounds__(256) void gemm1(const float* __restrict__ x,
                                             const float* __restrict__ W1,
                                             const float* __restrict__ a1s,
                                             const float* __restrict__ a1d,
                                             unsigned short* __restrict__ h1b,
                                             float2* __restrict__ alE,
                                             float* __restrict__ al1d) {
    __shared__ float sW[IN_DIM * HC];   // 32 KB
    int tid = threadIdx.x;
    const float4* W4 = (const float4*)W1;
    float4* sW4 = (float4*)sW;
#pragma unroll
    for (int i = 0; i < 8; i++)
        sW4[tid + i * 256] = W4[tid + i * 256];
    __syncthreads();

    int w = __builtin_amdgcn_readfirstlane(tid >> 6);
    int lane = tid & 63;
    int node0 = blockIdx.x * 16 + w * 4;       // 6250 blocks * 16 = 100000 exact
    const float* xr = x + (size_t)node0 * IN_DIM;

    float acc0 = 0.f, acc1 = 0.f, acc2 = 0.f, acc3 = 0.f;
#pragma unroll 8
    for (int k = 0; k < IN_DIM; k++) {
        float wv = sW[k * HC + lane];
        acc0 = fmaf(xr[k], wv, acc0);
        acc1 = fmaf(xr[IN_DIM + k], wv, acc1);
        acc2 = fmaf(xr[2 * IN_DIM + k], wv, acc2);
        acc3 = fmaf(xr[3 * IN_DIM + k], wv, acc3);
    }

    float accs[4] = {acc0, acc1, acc2, acc3};
    int head = lane >> 3, c = lane & 7;
    float as = a1s[head * NC1 + c], adv = a1d[head * NC1 + c];
#pragma unroll
    for (int n = 0; n < 4; n++) {
        int node = node0 + n;
        unsigned int u = __float_as_uint(accs[n]);
        h1b[node * HC + lane] =
            (unsigned short)((u + 0x7FFF + ((u >> 16) & 1)) >> 16);  // RNE bf16
        float ps = accs[n] * as;
        float pd = accs[n] * adv;
        for (int off = 1; off < 8; off <<= 1) {
            ps += __shfl_xor(ps, off, 64);
            pd += __shfl_xor(pd, off, 64);
        }
        if (c == 0) {
            alE[node * NH1 + head] = make_float2(exp2f(ps * L2E),
                                                 exp2f(ps * (NEGSL * L2E)));
            al1d[node * NH1 + head] = pd;
        }
    }
}

// ---------------- layer 1 aggregation (R11 structure — best measured) ----------------
// wave per node; TWO edges per wave-instruction: lane = ep*32 + c where
// ep = edge parity, c = channel pair (channels 2c,2c+1; head = c>>2).
// exp(LeakyReLU(als+ald)) == max(E1s*E1d, E2s*E2d); shift cancels in acc/den.

__global__ __launch_bounds__(256) void agg1(const unsigned short* __restrict__ h1b,
                                            const float2* __restrict__ alE,
                                            const float* __restrict__ al1d,
                                            const float* __restrict__ b1,
                                            const float* __restrict__ W2,
                                            const float* __restrict__ a2s,
                                            const float* __restrict__ a2d,
                                            const int* __restrict__ rowoff,
                                            const int* __restrict__ srcs,
                                            float4* __restrict__ nd2,
                                            float* __restrict__ al2d) {
    int w = threadIdx.x >> 6, lane = threadIdx.x & 63;
    int node = blockIdx.x * 4 + w;
    if (node >= NNODES) return;
    int ep = lane >> 5;          // which edge of the pair
    int c  = lane & 31;          // channel pair id: channels 2c, 2c+1
    int hh = c >> 2;             // head of both channels
    float ald = al1d[node * NH1 + hh];
    float E1d = exp2f(ald * L2E);
    float E2d = exp2f(ald * (NEGSL * L2E));
    int beg = __builtin_amdgcn_readfirstlane(rowoff[node]);
    int end = __builtin_amdgcn_readfirstlane(rowoff[node + 1]);

    float den = 0.f, acc0 = 0.f, acc1 = 0.f;
    float denB = 0.f, acc0B = 0.f, acc1B = 0.f;
    int i = beg;
    for (; i + 4 <= end; i += 4) {
        int sa = srcs[i + ep];
        int sb = srcs[i + 2 + ep];
        float2 ea = alE[sa * NH1 + hh];
        float2 eb = alE[sb * NH1 + hh];
        unsigned int ha = *(const unsigned int*)&h1b[sa * HC + 2 * c];
        unsigned int hb = *(const unsigned int*)&h1b[sb * HC + 2 * c];
        float pa = fmaxf(ea.x * E1d, ea.y * E2d);
        float pb = fmaxf(eb.x * E1d, eb.y * E2d);
        float va0 = __uint_as_float(ha << 16);
        float va1 = __uint_as_float(ha & 0xFFFF0000u);
        float vb0 = __uint_as_float(hb << 16);
        float vb1 = __uint_as_float(hb & 0xFFFF0000u);
        den  += pa;  acc0  = fmaf(pa, va0, acc0);  acc1  = fmaf(pa, va1, acc1);
        denB += pb;  acc0B = fmaf(pb, vb0, acc0B); acc1B = fmaf(pb, vb1, acc1B);
    }
    for (; i < end; i += 2) {
        int ia = i + ep;
        bool valid = ia < end;
        int sa = srcs[valid ? ia : end - 1];
        float2 ea = alE[sa * NH1 + hh];
        unsigned int ha = *(const unsigned int*)&h1b[sa * HC + 2 * c];
        float pa = fmaxf(ea.x * E1d, ea.y * E2d);
        pa = valid ? pa : 0.f;
        float va0 = __uint_as_float(ha << 16);
        float va1 = __uint_as_float(ha & 0xFFFF0000u);
        den += pa; acc0 = fmaf(pa, va0, acc0); acc1 = fmaf(pa, va1, acc1);
    }
    den += denB; acc0 += acc0B; acc1 += acc1B;
    den  += __shfl_xor(den, 32, 64);
    acc0 += __shfl_xor(acc0, 32, 64);
    acc1 += __shfl_xor(acc1, 32, 64);

    float2 b1v = *(const float2*)&b1[2 * c];
    float o0 = acc0 / den + b1v.x;
    float o1 = acc1 / den + b1v.y;
    o0 = (o0 > 0.f) ? o0 : expm1f(o0);       // ELU
    o1 = (o1 > 0.f) ? o1 : expm1f(o1);
    float4 w2v = *(const float4*)&W2[4 * c];
    float p0 = o0 * w2v.x + o1 * w2v.z;
    float p1 = o0 * w2v.y + o1 * w2v.w;
    for (int off = 1; off < 32; off <<= 1) {
        p0 += __shfl_xor(p0, off, 64);
        p1 += __shfl_xor(p1, off, 64);
    }
    if (lane == 0) {
        float l2s = p0 * a2s[0] + p1 * a2s[1];
        float l2d = p0 * a2d[0] + p1 * a2d[1];
        nd2[node] = make_float4(exp2f(l2s * L2E), exp2f(l2s * (NEGSL * L2E)),
                                p0, p1);
        al2d[node] = l2d;
    }
}

// ---------------- layer 2 aggregation (wave per node, lane per edge) ----------------

__global__ __launch_bounds__(256) void agg2(const float4* __restrict__ nd2,
                                            const float* __restrict__ al2d,
                                            const float* __restrict__ b2,
                                            const int* __restrict__ rowoff,
                                            const int* __restrict__ srcs,
                                            float* __restrict__ out) {
    int w = threadIdx.x >> 6, lane = threadIdx.x & 63;
    int n = blockIdx.x * 4 + w;
    if (n >= NNODES) return;
    float ald = al2d[n];
    float E1d = exp2f(ald * L2E);
    float E2d = exp2f(ald * (NEGSL * L2E));
    int beg = rowoff[n], end = rowoff[n + 1];
    float den = 0.f, a0 = 0.f, a1 = 0.f;
    for (int idx = beg + lane; idx < end; idx += 64) {
        int s = srcs[idx];
        float4 nd = nd2[s];
        float p = fmaxf(nd.x * E1d, nd.y * E2d);
        den += p;
        a0 = fmaf(p, nd.z, a0);
        a1 = fmaf(p, nd.w, a1);
    }
    for (int off = 1; off < 64; off <<= 1) {
        den += __shfl_xor(den, off, 64);
        a0  += __shfl_xor(a0, off, 64);
        a1  += __shfl_xor(a1, off, 64);
    }
    if (lane == 0) {
        out[n * 2 + 0] = a0 / den + b2[0];
        out[n * 2 + 1] = a1 / den + b2[1];
    }
}

// ---------------- launch ----------------

extern "C" void kernel_launch(void* const* d_in, const int* in_sizes, int n_in,
                              void* d_out, int out_size, void* d_ws, size_t ws_size,
                              hipStream_t stream) {
    const float* x   = (const float*)d_in[0];
    const int*   ei  = (const int*)  d_in[1];
    // d_in[2] = edge_attr (unused by reference)
    const float* W1  = (const float*)d_in[3];
    const float* a1s = (const float*)d_in[4];
    const float* a1d = (const float*)d_in[5];
    const float* b1  = (const float*)d_in[6];
    const float* W2  = (const float*)d_in[7];
    const float* a2s = (const float*)d_in[8];
    const float* a2d = (const float*)d_in[9];
    const float* b2  = (const float*)d_in[10];
    float* out = (float*)d_out;

    // workspace layout. CSR scratch (ebuf/carr/bsums) aliases the h1b+alE
    // region — both are dead until gemm1, which runs after buildD.
    char* ws = (char*)d_ws;
    unsigned short* h1b = (unsigned short*)ws;               // N*64 bf16 (12.8MB)
    float2* alE   = (float2*)(ws + (size_t)NNODES * HC * 2); // N*8 float2 (6.4MB)
    float* al1d_  = (float*)(alE + (size_t)NNODES * NH1);    // N*8 (3.2MB)
    float4* nd2   = (float4*)(al1d_ + (size_t)NNODES * NH1); // N float4 (1.6MB)
    float* al2d_  = (float*)(nd2 + NNODES);                  // N
    int* rowoff   = (int*)(al2d_ + NNODES);                  // N+1
    int* srcs     = rowoff + NNODES + 1;                     // E+N (13.2MB)
    // CSR scratch aliases h1b..alE (19.2MB >= 14.1MB needed)
    int* ebuf     = (int*)ws;                                // NEDGES (12.8MB)
    int* carr     = ebuf + NEDGES;                           // TOTC (1.22MB)
    int* bsums    = carr + TOTC;                             // ~1195 ints

    const int NB_SC  = (TOTC + 255) / 256;            // 1195
    const int NB_N4  = (NNODES + 3) / 4;              // 25000
    const int NB_G   = NNODES / 16;                   // 6250 (exact)

    // CSR build (LDS counting sort; no global atomics)
    histA<<<NBLK, 256, 0, stream>>>(ei, carr);
    scanA<<<NB_SC, 256, 0, stream>>>(carr, bsums);
    scanB<<<1, 1024, 0, stream>>>(bsums, NB_SC);
    scanC<<<NB_SC, 256, 0, stream>>>(carr, bsums);
    scatC<<<NBLK, 256, 0, stream>>>(ei, carr, ebuf);
    buildD<<<NBUCK, 256, 0, stream>>>(carr, ebuf, rowoff, srcs);

    // layer 1 linear + logit exponentials
    gemm1<<<NB_G, 256, 0, stream>>>(x, W1, a1s, a1d, h1b, alE, al1d_);

    // layer 1 aggregation + finalize + layer-2 linear/logits
    agg1<<<NB_N4, 256, 0, stream>>>(h1b, alE, al1d_, b1, W2, a2s, a2d,
                                    rowoff, srcs, nd2, al2d_);

    // layer 2 aggregation -> output
    agg2<<<NB_N4, 256, 0, stream>>>(nd2, al2d_, b2, rowoff, srcs, out);
}